// Round 10
// baseline (266.662 us; speedup 1.0000x reference)
//
#include <hip/hip_runtime.h>
#include <hip/hip_cooperative_groups.h>

namespace cg = cooperative_groups;

#define NN    4096      // nodes
#define DD    256       // feature dim (= H*HID)
#define NH    4         // heads
#define HIDD  64        // per-head hidden
#define NE    131072    // edges
#define WPR   (NN/32)   // 128 u32 words per adjacency bitmask row
#define SLOPE 0.2f
#define CAP   128       // max degree; Binom(131072,1/4096) max ~56 incl self
#define GRID  1024

typedef __attribute__((ext_vector_type(8))) short short8;   // 8 bf16 in 4 VGPRs
typedef __attribute__((ext_vector_type(4))) float f32x4;

__device__ __forceinline__ unsigned short f2bf(float x) {   // RNE, matches HW cvt
    unsigned u = __float_as_uint(x);
    u += 0x7fffu + ((u >> 16) & 1u);
    return (unsigned short)(u >> 16);
}
__device__ __forceinline__ float bf2f(unsigned short v) {
    return __uint_as_float((unsigned)v << 16);
}
__device__ __forceinline__ unsigned pack2(float a, float b) {
    return (unsigned)f2bf(a) | ((unsigned)f2bf(b) << 16);
}

// ONE cooperative kernel, 1024 blocks x 256 thr (4 blk/CU co-resident).
// P0: Ab=bf16(in) (coalesced), Wt=bf16(W^T) (LDS tile, blocks 0..15),
//     adj zero + self-loop bit composed in (owned slices).
// sync
// P1: edge atomicOr (128 edges/block)  +  MFMA GEMM (block = 16 rows x 1
//     head; wave = 16x16 tile; 8x mfma_f32_16x16x32_bf16) + fused e1/e2.
// sync
// P2: per-WAVE GAT row (i = 4b+wv): bit-scan -> wgt/nbr in LDS, Z by wave
//     shuffle only, gather 4 heads/lane, ELU. (R9 lesson: multi-node graphs
//     carry ~20us of unattributable inter-node overhead -> fuse to 1 node.)
__global__ __launch_bounds__(256, 4) void gat_fused(
    const float* __restrict__ in, const int* __restrict__ edges,
    const float* __restrict__ W, const float* __restrict__ att,
    float* __restrict__ out,
    unsigned short* __restrict__ Ab, unsigned short* __restrict__ Wt,
    unsigned short* __restrict__ Whb, float* __restrict__ e1,
    float* __restrict__ e2, unsigned int* __restrict__ adj) {
    cg::grid_group grid = cg::this_grid();
    int b = blockIdx.x, t = threadIdx.x;
    int lane = t & 63, wv = t >> 6;

    __shared__ unsigned short tile[64][68];       // P0 W-transpose (blocks<16)
    __shared__ float s1[4][16], s2[4][16];        // P1 e1/e2 combine
    __shared__ int   nbr[4][CAP];                 // P2 per-wave neighbor lists
    __shared__ float wgt[4][CAP][NH];
    __shared__ int   cnt[4];

    // ---------------- P0: prep ----------------
    {   // Ab: 262144 float4 over 1024 blocks -> 1/thread, fully coalesced
        int e = b * 256 + t;
        float4 v = ((const float4*)in)[e];
        ((uint2*)Ab)[e] = uint2{pack2(v.x, v.y), pack2(v.z, v.w)};
    }
    if (t < 128) {                                // adj zero + self bit; 128 uint4/block
        int g = b * 128 + t;                      // uint4 index; 32 per row
        int r = g >> 5;
        int sw = r * WPR + (r >> 5);              // word holding row r's self bit
        uint4 z{0u, 0u, 0u, 0u};
        if ((sw >> 2) == g) ((unsigned*)&z)[sw & 3] = 1u << (r & 31);
        ((uint4*)adj)[g] = z;
    }
    if (b < 16) {                                 // Wt[c][k] = bf16(W[k][c])
        int tr = b >> 2, tc = b & 3;
        int k0 = tr * 64, c0 = tc * 64;
        #pragma unroll
        for (int i = 0; i < 16; ++i) {
            int e = i * 256 + t, r = e >> 6, c = e & 63;
            tile[r][c] = f2bf(W[(k0 + r) * DD + c0 + c]);
        }
        __syncthreads();                          // block-uniform branch: safe
        #pragma unroll
        for (int i = 0; i < 16; ++i) {
            int e = i * 256 + t, cc = e >> 6, rr = e & 63;
            Wt[(c0 + cc) * DD + k0 + rr] = tile[rr][cc];
        }
    }
    grid.sync();

    // ---------------- P1: edge bits + MFMA GEMM + e1/e2 ----------------
    if (t < 128) {                                // 128 edges/block, dedup by OR
        int idx = b * 128 + t;
        int r = edges[idx * 3 + 0];
        int c = edges[idx * 3 + 1];
        atomicOr(&adj[r * WPR + (c >> 5)], 1u << (c & 31));
    }
    {
        int rt = b >> 2, head = b & 3;
        int row0 = rt * 16;
        int col0 = head * 64 + wv * 16;
        const unsigned short* Arow = Ab + (row0 + (lane & 15)) * DD;
        const unsigned short* Brow = Wt + (col0 + (lane & 15)) * DD;
        int kb = (lane >> 4) * 8;
        f32x4 acc = {0.f, 0.f, 0.f, 0.f};
        #pragma unroll
        for (int s = 0; s < 8; ++s) {
            int k = s * 32 + kb;
            short8 af = *(const short8*)(Arow + k);
            short8 bf = *(const short8*)(Brow + k);
            acc = __builtin_amdgcn_mfma_f32_16x16x32_bf16(af, bf, acc, 0, 0, 0);
        }
        // C/D: col=lane&15, row=(lane>>4)*4+r (m89-verified)
        int rg = lane >> 4, cl = lane & 15;
        int crow = row0 + rg * 4;
        int ccol = col0 + cl;
        float a1w = att[wv * 16 + cl];
        float a2w = att[HIDD + wv * 16 + cl];
        float p1[4], p2[4];
        #pragma unroll
        for (int r = 0; r < 4; ++r) {
            Whb[(crow + r) * DD + ccol] = f2bf(acc[r]);
            p1[r] = acc[r] * a1w;
            p2[r] = acc[r] * a2w;
        }
        #pragma unroll
        for (int off = 1; off < 16; off <<= 1) {
            #pragma unroll
            for (int r = 0; r < 4; ++r) {
                p1[r] += __shfl_xor(p1[r], off);
                p2[r] += __shfl_xor(p2[r], off);
            }
        }
        if (cl == 0) {
            #pragma unroll
            for (int r = 0; r < 4; ++r) {
                s1[wv][rg * 4 + r] = p1[r];
                s2[wv][rg * 4 + r] = p2[r];
            }
        }
        __syncthreads();
        if (t < 16) {
            e1[(row0 + t) * NH + head] = s1[0][t] + s1[1][t] + s1[2][t] + s1[3][t];
            e2[(row0 + t) * NH + head] = s2[0][t] + s2[1][t] + s2[2][t] + s2[3][t];
        }
    }
    grid.sync();

    // ---------------- P2: per-wave GAT row ----------------
    {
        int i = b * 4 + wv;                       // this wave's node
        if (lane == 0) cnt[wv] = 0;               // wave-coherent LDS
        float4 e1q = *(const float4*)(e1 + i * NH);
        float  e1v[NH] = {e1q.x, e1q.y, e1q.z, e1q.w};

        // scan 128 words with 64 lanes (2 words/lane); weights inline
        float zl[NH] = {0.f, 0.f, 0.f, 0.f};
        #pragma unroll
        for (int q = 0; q < 2; ++q) {
            unsigned bits = adj[i * WPR + q * 64 + lane];
            while (bits) {
                int bp = __ffs(bits) - 1;
                bits &= bits - 1;
                int j = (q * 64 + lane) * 32 + bp;
                int d = atomicAdd(&cnt[wv], 1);
                if (d < CAP) {
                    nbr[wv][d] = j;
                    float4 ev = *(const float4*)(e2 + j * NH);
                    float e2v[NH] = {ev.x, ev.y, ev.z, ev.w};
                    #pragma unroll
                    for (int h = 0; h < NH; ++h) {
                        float s = e1v[h] + e2v[h];
                        s = (s >= 0.f) ? s : SLOPE * s;   // LeakyReLU
                        float w = __expf(s);
                        wgt[wv][d][h] = w;
                        zl[h] += w;
                    }
                }
            }
        }
        #pragma unroll
        for (int off = 32; off; off >>= 1) {
            #pragma unroll
            for (int h = 0; h < NH; ++h) zl[h] += __shfl_xor(zl[h], off);
        }
        __syncthreads();                          // nbr/wgt/cnt visible (belt+braces)
        int cn = cnt[wv];
        if (cn > CAP) cn = CAP;

        float acc[NH] = {0.f, 0.f, 0.f, 0.f};
        for (int d = 0; d < cn; ++d) {
            int j = nbr[wv][d];
            const unsigned short* row = Whb + j * DD + lane;
            #pragma unroll
            for (int h = 0; h < NH; ++h)          // 128B coalesced per (d,h)
                acc[h] = fmaf(wgt[wv][d][h], bf2f(row[h * HIDD]), acc[h]);
        }
        #pragma unroll
        for (int h = 0; h < NH; ++h) {
            float r = acc[h] / zl[h];
            out[i * DD + h * HIDD + lane] = (r > 0.f) ? r : (__expf(r) - 1.f);
        }
    }
}

// ---------------------------------------------------------------- launcher
extern "C" void kernel_launch(void* const* d_in, const int* in_sizes, int n_in,
                              void* d_out, int out_size, void* d_ws, size_t ws_size,
                              hipStream_t stream) {
    const float* inp   = (const float*)d_in[0];
    const int*   edges = (const int*)d_in[1];
    // d_in[2] = num_node (scalar, constant 4096) — unused
    const float* W     = (const float*)d_in[3];
    const float* att   = (const float*)d_in[4];
    float*       out   = (float*)d_out;

    char* ws = (char*)d_ws;
    unsigned short* Whb = (unsigned short*)(ws);                           // 2 MB
    float*          e1  = (float*)(ws + (2u << 20));                       // 64 KB
    float*          e2  = (float*)(ws + (2u << 20) + (64u << 10));         // 64 KB
    unsigned int*   adj = (unsigned int*)(ws + (2u << 20) + (128u << 10)); // 2 MB
    unsigned short* Ab  = (unsigned short*)(ws + (4u << 20) + (128u << 10)); // 2 MB
    unsigned short* Wt  = (unsigned short*)(ws + (6u << 20) + (128u << 10)); // 128 KB

    void* args[] = {(void*)&inp, (void*)&edges, (void*)&W, (void*)&att,
                    (void*)&out, (void*)&Ab, (void*)&Wt, (void*)&Whb,
                    (void*)&e1, (void*)&e2, (void*)&adj};
    (void)hipLaunchCooperativeKernel((const void*)gat_fused, dim3(GRID), dim3(256),
                                     args, 0, stream);
}

// Round 11
// 58.500 us; speedup vs baseline: 4.5583x; 4.5583x over previous
//
#include <hip/hip_runtime.h>

#define NN    4096      // nodes
#define DD    256       // feature dim (= H*HID)
#define NH    4         // heads
#define HIDD  64        // per-head hidden
#define NE    131072    // edges
#define WPR   (NN/32)   // 128 u32 words per adjacency bitmask row
#define SLOPE 0.2f
#define CAP   128       // max degree; Binom(131072,1/4096) max over 4096 rows ~56 incl self

typedef __attribute__((ext_vector_type(8))) short short8;   // 8 bf16 in 4 VGPRs
typedef __attribute__((ext_vector_type(4))) float f32x4;

__device__ __forceinline__ unsigned short f2bf(float x) {   // RNE, matches HW cvt
    unsigned u = __float_as_uint(x);
    u += 0x7fffu + ((u >> 16) & 1u);
    return (unsigned short)(u >> 16);
}
__device__ __forceinline__ float bf2f(unsigned short v) {
    return __uint_as_float((unsigned)v << 16);
}

// ---------------------------------------------------------------- K1: MFMA GEMM + adj-zero/self-loops + fused e1/e2
// (R8 kernel, unchanged. PROBE THIS ROUND: launched TWICE — it is a pure
// function of in/W/att, so the replay is deterministic and the dur delta
// vs R8's 42.4us measures k1's true in-replay cost, bypassing the
// fill-clogged rocprof top-5.)
__global__ __launch_bounds__(256) void k1_mfma_gemm(
    const float* __restrict__ in, const float* __restrict__ W,
    const float* __restrict__ att, unsigned short* __restrict__ Whb,
    float* __restrict__ e1, float* __restrict__ e2,
    unsigned int* __restrict__ adj) {
    int b = blockIdx.x;
    int t = threadIdx.x;
    int lane = t & 63, wv = t >> 6;
    int rt = b >> 2, head = b & 3;
    int row0 = rt * 16;
    int col0 = head * 64 + wv * 16;

    if (head == 0) {
        uint4* adj4 = (uint4*)adj;
        #pragma unroll
        for (int q = 0; q < 2; ++q) {
            int g = rt * 512 + q * 256 + t;     // global uint4 index; 32 per row
            int r = g >> 5;                      // the row this uint4 belongs to
            int sw = r * 128 + (r >> 5);         // word holding row r's self bit
            uint4 z{0u, 0u, 0u, 0u};
            if ((sw >> 2) == g) ((unsigned*)&z)[sw & 3] = 1u << (r & 31);
            adj4[g] = z;
        }
    }

    // ---- MFMA GEMM
    const float* Arow = in + (row0 + (lane & 15)) * DD;
    const float* Bcol = W + col0 + (lane & 15);
    int kb = (lane >> 4) * 8;
    f32x4 acc = {0.f, 0.f, 0.f, 0.f};
    #pragma unroll
    for (int s = 0; s < 8; ++s) {
        int k = s * 32 + kb;
        float4 x0 = *(const float4*)(Arow + k);
        float4 x1 = *(const float4*)(Arow + k + 4);
        short8 af, bfr;
        af[0] = (short)f2bf(x0.x); af[1] = (short)f2bf(x0.y);
        af[2] = (short)f2bf(x0.z); af[3] = (short)f2bf(x0.w);
        af[4] = (short)f2bf(x1.x); af[5] = (short)f2bf(x1.y);
        af[6] = (short)f2bf(x1.z); af[7] = (short)f2bf(x1.w);
        #pragma unroll
        for (int j = 0; j < 8; ++j) bfr[j] = (short)f2bf(Bcol[(k + j) * DD]);
        acc = __builtin_amdgcn_mfma_f32_16x16x32_bf16(af, bfr, acc, 0, 0, 0);
    }

    // ---- store C (bf16) + e1/e2 epilogue
    int rg = lane >> 4, cl = lane & 15;
    int crow = row0 + rg * 4;
    int ccol = col0 + cl;
    float a1w = att[wv * 16 + cl];           // f = col within head
    float a2w = att[HIDD + wv * 16 + cl];
    float p1[4], p2[4];
    #pragma unroll
    for (int r = 0; r < 4; ++r) {
        Whb[(crow + r) * DD + ccol] = f2bf(acc[r]);
        p1[r] = acc[r] * a1w;
        p2[r] = acc[r] * a2w;
    }
    #pragma unroll
    for (int off = 1; off < 16; off <<= 1) {   // reduce over the 16 cols
        #pragma unroll
        for (int r = 0; r < 4; ++r) {
            p1[r] += __shfl_xor(p1[r], off);
            p2[r] += __shfl_xor(p2[r], off);
        }
    }
    __shared__ float s1[4][16], s2[4][16];     // [wave][row-in-tile]
    if (cl == 0) {
        #pragma unroll
        for (int r = 0; r < 4; ++r) {
            s1[wv][rg * 4 + r] = p1[r];
            s2[wv][rg * 4 + r] = p2[r];
        }
    }
    __syncthreads();
    if (t < 16) {
        float v1 = s1[0][t] + s1[1][t] + s1[2][t] + s1[3][t];
        float v2 = s2[0][t] + s2[1][t] + s2[2][t] + s2[3][t];
        e1[(row0 + t) * NH + head] = v1;
        e2[(row0 + t) * NH + head] = v2;
    }
}

// ---------------------------------------------------------------- K2: edge bits (dedup via idempotent OR)
__global__ __launch_bounds__(256) void k2_build(
    const int* __restrict__ edges, unsigned int* __restrict__ adj) {
    int t = blockIdx.x * 256 + threadIdx.x;        // grid == NE exactly
    int r = edges[t * 3 + 0];
    int c = edges[t * 3 + 1];
    atomicOr(&adj[r * WPR + (c >> 5)], 1u << (c & 31));
}

// ---------------------------------------------------------------- K3: per-row GAT (no max-trick: logits small, fp32 exp exact ratio)
__global__ __launch_bounds__(256) void k3_gat(
    const unsigned int* __restrict__ adj, const unsigned short* __restrict__ Whb,
    const float* __restrict__ e1, const float* __restrict__ e2,
    float* __restrict__ out) {
    int i    = blockIdx.x;
    int t    = threadIdx.x;
    int lane = t & 63, wid = t >> 6;

    __shared__ int   nbr[CAP];
    __shared__ float wgt[CAP][NH];
    __shared__ int   cnt;
    __shared__ float zred[4][NH];

    if (t == 0) cnt = 0;
    __syncthreads();

    float4 e1q = *(const float4*)(e1 + i * NH);
    float  e1v[NH] = {e1q.x, e1q.y, e1q.z, e1q.w};

    // ---- scan bitmask row; softmax numerators inline
    float zl[NH] = {0.f, 0.f, 0.f, 0.f};
    if (t < WPR) {
        unsigned int bits = adj[i * WPR + t];
        while (bits) {
            int bpos = __ffs(bits) - 1;
            bits &= bits - 1;
            int j = t * 32 + bpos;
            int d = atomicAdd(&cnt, 1);
            if (d < CAP) {
                nbr[d] = j;
                float4 ev = *(const float4*)(e2 + j * NH);
                float e2v[NH] = {ev.x, ev.y, ev.z, ev.w};
                #pragma unroll
                for (int h = 0; h < NH; ++h) {
                    float s = e1v[h] + e2v[h];
                    s = (s >= 0.f) ? s : SLOPE * s;      // LeakyReLU
                    float w = __expf(s);
                    wgt[d][h] = w;
                    zl[h] += w;
                }
            }
        }
    }
    // ---- block reduce Z
    #pragma unroll
    for (int off = 32; off; off >>= 1) {
        #pragma unroll
        for (int h = 0; h < NH; ++h) zl[h] += __shfl_xor(zl[h], off);
    }
    if (lane == 0) {
        #pragma unroll
        for (int h = 0; h < NH; ++h) zred[wid][h] = zl[h];
    }
    __syncthreads();               // wgt/nbr/cnt/zred visible

    float Z = zred[0][wid] + zred[1][wid] + zred[2][wid] + zred[3][wid];
    int cn = cnt;
    if (cn > CAP) cn = CAP;

    // ---- gather: thread (h=wid, f=lane); bf16 row segment = 128B coalesced/wave
    float acc = 0.f;
    #pragma unroll 8
    for (int d = 0; d < cn; ++d)
        acc = fmaf(wgt[d][wid],
                   bf2f(Whb[nbr[d] * DD + wid * HIDD + lane]), acc);
    float r = acc / Z;
    out[i * DD + t] = (r > 0.f) ? r : (__expf(r) - 1.f);   // ELU(alpha=1)
}

// ---------------------------------------------------------------- launcher
extern "C" void kernel_launch(void* const* d_in, const int* in_sizes, int n_in,
                              void* d_out, int out_size, void* d_ws, size_t ws_size,
                              hipStream_t stream) {
    const float* inp   = (const float*)d_in[0];
    const int*   edges = (const int*)d_in[1];
    // d_in[2] = num_node (scalar, constant 4096) — unused
    const float* W     = (const float*)d_in[3];
    const float* att   = (const float*)d_in[4];
    float*       out   = (float*)d_out;

    char* ws = (char*)d_ws;
    unsigned short* Whb = (unsigned short*)(ws);                   // 2 MB
    float*        e1  = (float*)(ws + (2u << 20));                 // 64 KB
    float*        e2  = (float*)(ws + (2u << 20) + (64u << 10));   // 64 KB
    unsigned int* adj = (unsigned int*)(ws + (2u << 20) + (128u << 10)); // 2 MB

    // PROBE: k1 twice (idempotent). dur - 42.4us == true k1 replay cost.
    k1_mfma_gemm<<<NN / 16 * NH, 256, 0, stream>>>(inp, W, att, Whb, e1, e2, adj);
    k1_mfma_gemm<<<NN / 16 * NH, 256, 0, stream>>>(inp, W, att, Whb, e1, e2, adj);
    k2_build<<<NE / 256, 256, 0, stream>>>(edges, adj);
    k3_gat<<<NN, 256, 0, stream>>>(adj, Whb, e1, e2, out);
}

// Round 12
// 42.992 us; speedup vs baseline: 6.2026x; 1.3607x over previous
//
#include <hip/hip_runtime.h>

#define NN    4096      // nodes
#define DD    256       // feature dim (= H*HID)
#define NH    4         // heads
#define HIDD  64        // per-head hidden
#define NE    131072    // edges
#define WPR   (NN/32)   // 128 u32 words per adjacency bitmask row
#define SLOPE 0.2f
#define CAP   128       // max degree; Binom(131072,1/4096) max over 4096 rows ~56 incl self
#define LDB   264       // padded LDS leading dim (bf16): 528B rows -> 2-way banks on frags

typedef __attribute__((ext_vector_type(8))) short short8;   // 8 bf16 in 4 VGPRs
typedef __attribute__((ext_vector_type(4))) float f32x4;

__device__ __forceinline__ unsigned short f2bf(float x) {   // RNE, matches HW cvt
    unsigned u = __float_as_uint(x);
    u += 0x7fffu + ((u >> 16) & 1u);
    return (unsigned short)(u >> 16);
}
__device__ __forceinline__ float bf2f(unsigned short v) {
    return __uint_as_float((unsigned)v << 16);
}

// ---------------------------------------------------------------- K1: MFMA GEMM (LDS-staged) + adj-zero/self + fused e1/e2
// 1024 blocks. Block b: rows [16(b>>2),+16) x head (b&3). Staging:
// coalesced float4 global reads -> bf16 LDS (A-tile 16x256; B-panel 64x256
// stored TRANSPOSED [c][k]); fragments via ds_read_b128 (16/wave). This
// removes R8's 16-line-split strided gathers and in-loop f2bf (R11 probe:
// k1 node was 16.1us; exec ~9us was operand-path cost).
__global__ __launch_bounds__(256) void k1_mfma_gemm(
    const float* __restrict__ in, const float* __restrict__ W,
    const float* __restrict__ att, unsigned short* __restrict__ Whb,
    float* __restrict__ e1, float* __restrict__ e2,
    unsigned int* __restrict__ adj) {
    int b = blockIdx.x;
    int t = threadIdx.x;
    int lane = t & 63, wv = t >> 6;
    int rt = b >> 2, head = b & 3;
    int row0 = rt * 16;
    int col0 = head * 64;

    __shared__ unsigned short As[16][LDB];
    __shared__ unsigned short Bs[64][LDB];
    __shared__ float s1[4][16], s2[4][16];

    // adj zero + self bits (head-0 blocks own rows [16rt,+16) = 512 uint4)
    if (head == 0) {
        uint4* adj4 = (uint4*)adj;
        #pragma unroll
        for (int q = 0; q < 2; ++q) {
            int g = rt * 512 + q * 256 + t;
            int r = g >> 5;
            int sw = r * WPR + (r >> 5);
            uint4 z{0u, 0u, 0u, 0u};
            if ((sw >> 2) == g) ((unsigned*)&z)[sw & 3] = 1u << (r & 31);
            adj4[g] = z;
        }
    }

    // ---- stage A: 16x256 fp32 -> bf16, 1024 float4 coalesced
    {
        const float4* src = (const float4*)(in + row0 * DD);
        #pragma unroll
        for (int i = 0; i < 4; ++i) {
            int e = i * 256 + t;
            int r = e >> 6, c4 = (e & 63) * 4;
            float4 v = src[e];
            unsigned short* dst = &As[r][c4];
            ((uint2*)dst)[0] = uint2{
                (unsigned)f2bf(v.x) | ((unsigned)f2bf(v.y) << 16),
                (unsigned)f2bf(v.z) | ((unsigned)f2bf(v.w) << 16)};
        }
    }
    // ---- stage B transposed: Bs[c][k] = bf16(W[k][col0+c]); 16 passes
    {
        int c4 = (t & 15) * 4;
        int kk = t >> 4;
        #pragma unroll
        for (int i = 0; i < 16; ++i) {
            int k = i * 16 + kk;
            float4 w = *(const float4*)(W + k * DD + col0 + c4);
            Bs[c4 + 0][k] = f2bf(w.x);
            Bs[c4 + 1][k] = f2bf(w.y);
            Bs[c4 + 2][k] = f2bf(w.z);
            Bs[c4 + 3][k] = f2bf(w.w);
        }
    }
    __syncthreads();

    // ---- MFMA: wave wv = 16x16 tile at local cols [16wv,+16), K=256
    const unsigned short* Ap = &As[lane & 15][0];
    const unsigned short* Bp = &Bs[wv * 16 + (lane & 15)][0];
    int kb = (lane >> 4) * 8;
    f32x4 acc = {0.f, 0.f, 0.f, 0.f};
    #pragma unroll
    for (int s = 0; s < 8; ++s) {
        int k = s * 32 + kb;
        short8 af = *(const short8*)(Ap + k);
        short8 bf = *(const short8*)(Bp + k);
        acc = __builtin_amdgcn_mfma_f32_16x16x32_bf16(af, bf, acc, 0, 0, 0);
    }

    // ---- store C (bf16) + e1/e2 epilogue (C/D: col=lane&15, row=(lane>>4)*4+r)
    int rg = lane >> 4, cl = lane & 15;
    int crow = row0 + rg * 4;
    int ccol = col0 + wv * 16 + cl;
    float a1w = att[wv * 16 + cl];
    float a2w = att[HIDD + wv * 16 + cl];
    float p1[4], p2[4];
    #pragma unroll
    for (int r = 0; r < 4; ++r) {
        Whb[(crow + r) * DD + ccol] = f2bf(acc[r]);
        p1[r] = acc[r] * a1w;
        p2[r] = acc[r] * a2w;
    }
    #pragma unroll
    for (int off = 1; off < 16; off <<= 1) {
        #pragma unroll
        for (int r = 0; r < 4; ++r) {
            p1[r] += __shfl_xor(p1[r], off);
            p2[r] += __shfl_xor(p2[r], off);
        }
    }
    if (cl == 0) {
        #pragma unroll
        for (int r = 0; r < 4; ++r) {
            s1[wv][rg * 4 + r] = p1[r];
            s2[wv][rg * 4 + r] = p2[r];
        }
    }
    __syncthreads();
    if (t < 16) {
        e1[(row0 + t) * NH + head] = s1[0][t] + s1[1][t] + s1[2][t] + s1[3][t];
        e2[(row0 + t) * NH + head] = s2[0][t] + s2[1][t] + s2[2][t] + s2[3][t];
    }
}

// ---------------------------------------------------------------- K2: edge bits (dedup via idempotent OR)
__global__ __launch_bounds__(256) void k2_build(
    const int* __restrict__ edges, unsigned int* __restrict__ adj) {
    int t = blockIdx.x * 256 + threadIdx.x;        // grid == NE exactly
    int r = edges[t * 3 + 0];
    int c = edges[t * 3 + 1];
    atomicOr(&adj[r * WPR + (c >> 5)], 1u << (c & 31));
}

// ---------------------------------------------------------------- K3: per-row GAT (prefix-scan compaction; no LDS-atomic chain)
__global__ __launch_bounds__(256) void k3_gat(
    const unsigned int* __restrict__ adj, const unsigned short* __restrict__ Whb,
    const float* __restrict__ e1, const float* __restrict__ e2,
    float* __restrict__ out) {
    int i    = blockIdx.x;
    int t    = threadIdx.x;
    int lane = t & 63, wid = t >> 6;

    __shared__ int   nbr[CAP];
    __shared__ float wgt[CAP][NH];
    __shared__ float zred[4][NH];
    __shared__ int   wtot[2];

    float4 e1q = *(const float4*)(e1 + i * NH);
    float  e1v[NH] = {e1q.x, e1q.y, e1q.z, e1q.w};

    // ---- scan 128 words: popcount -> wave prefix sum -> compacted writes
    unsigned wword = 0;
    int pc = 0;
    if (t < WPR) {
        wword = adj[i * WPR + t];
        pc = __popc(wword);
    }
    int incl = pc;
    #pragma unroll
    for (int off = 1; off < 64; off <<= 1) {
        int v = __shfl_up(incl, off);
        if (lane >= off) incl += v;
    }
    if (wid < 2 && lane == 63) wtot[wid] = incl;
    __syncthreads();
    int start = (wid == 1 ? wtot[0] : 0) + incl - pc;   // exclusive prefix
    int cn = wtot[0] + wtot[1];
    if (cn > CAP) cn = CAP;

    float zl[NH] = {0.f, 0.f, 0.f, 0.f};
    if (t < WPR) {
        int d = start;
        unsigned bits = wword;
        while (bits) {
            int bp = __ffs(bits) - 1;
            bits &= bits - 1;
            int j = t * 32 + bp;
            if (d < CAP) {
                nbr[d] = j;
                float4 ev = *(const float4*)(e2 + j * NH);
                float e2v[NH] = {ev.x, ev.y, ev.z, ev.w};
                #pragma unroll
                for (int h = 0; h < NH; ++h) {
                    float s = e1v[h] + e2v[h];
                    s = (s >= 0.f) ? s : SLOPE * s;      // LeakyReLU
                    float w = __expf(s);
                    wgt[d][h] = w;
                    zl[h] += w;
                }
            }
            ++d;
        }
    }
    // ---- block reduce Z (waves 2,3 contribute zeros)
    #pragma unroll
    for (int off = 32; off; off >>= 1) {
        #pragma unroll
        for (int h = 0; h < NH; ++h) zl[h] += __shfl_xor(zl[h], off);
    }
    if (lane == 0) {
        #pragma unroll
        for (int h = 0; h < NH; ++h) zred[wid][h] = zl[h];
    }
    __syncthreads();               // nbr/wgt/zred visible

    float Z = zred[0][wid] + zred[1][wid] + zred[2][wid] + zred[3][wid];

    // ---- gather: thread (h=wid, f=lane); bf16 row segment = 128B coalesced/wave
    float acc = 0.f;
    #pragma unroll 8
    for (int d = 0; d < cn; ++d)
        acc = fmaf(wgt[d][wid],
                   bf2f(Whb[nbr[d] * DD + wid * HIDD + lane]), acc);
    float r = acc / Z;
    out[i * DD + t] = (r > 0.f) ? r : (__expf(r) - 1.f);   // ELU(alpha=1)
}

// ---------------------------------------------------------------- launcher
extern "C" void kernel_launch(void* const* d_in, const int* in_sizes, int n_in,
                              void* d_out, int out_size, void* d_ws, size_t ws_size,
                              hipStream_t stream) {
    const float* inp   = (const float*)d_in[0];
    const int*   edges = (const int*)d_in[1];
    // d_in[2] = num_node (scalar, constant 4096) — unused
    const float* W     = (const float*)d_in[3];
    const float* att   = (const float*)d_in[4];
    float*       out   = (float*)d_out;

    char* ws = (char*)d_ws;
    unsigned short* Whb = (unsigned short*)(ws);                   // 2 MB
    float*        e1  = (float*)(ws + (2u << 20));                 // 64 KB
    float*        e2  = (float*)(ws + (2u << 20) + (64u << 10));   // 64 KB
    unsigned int* adj = (unsigned int*)(ws + (2u << 20) + (128u << 10)); // 2 MB

    k1_mfma_gemm<<<NN / 16 * NH, 256, 0, stream>>>(inp, W, att, Whb, e1, e2, adj);
    k2_build<<<NE / 256, 256, 0, stream>>>(edges, adj);
    k3_gat<<<NN, 256, 0, stream>>>(adj, Whb, e1, e2, out);
}

// Round 13
// 42.393 us; speedup vs baseline: 6.2902x; 1.0141x over previous
//
#include <hip/hip_runtime.h>

#define NN    4096      // nodes
#define DD    256       // feature dim (= H*HID)
#define NH    4         // heads
#define HIDD  64        // per-head hidden
#define NE    131072    // edges
#define WPR   (NN/32)   // 128 u32 words per adjacency bitmask row
#define SLOPE 0.2f
#define CAP   128       // max degree; Binom(131072,1/4096) max over 4096 rows ~56 incl self
#define LDA   264       // As leading dim (bf16): 528B rows -> 2-way banks on frags
#define LDBH  136       // Bs leading dim for K=128 half (272B rows, same 2-way pattern)

typedef __attribute__((ext_vector_type(8))) short short8;   // 8 bf16 in 4 VGPRs
typedef __attribute__((ext_vector_type(4))) float f32x4;

__device__ __forceinline__ unsigned short f2bf(float x) {   // RNE, matches HW cvt
    unsigned u = __float_as_uint(x);
    u += 0x7fffu + ((u >> 16) & 1u);
    return (unsigned short)(u >> 16);
}
__device__ __forceinline__ float bf2f(unsigned short v) {
    return __uint_as_float((unsigned)v << 16);
}

// ---------------------------------------------------------------- K1: MFMA GEMM (LDS-staged, half-K dbuf) + adj-zero/self + e1/e2
// 1024 blocks. R12 lesson: 42.8KB LDS -> 3 blocks/CU but grid needs 4/CU
// -> two dispatch waves + thin latency hiding. This version stages B in two
// K=128 half-phases reusing one 17.4KB buffer: total ~26.3KB -> 4 blocks/CU
// (pinned via __launch_bounds__(256,4)), whole grid co-resident.
__global__ __launch_bounds__(256, 4) void k1_mfma_gemm(
    const float* __restrict__ in, const float* __restrict__ W,
    const float* __restrict__ att, unsigned short* __restrict__ Whb,
    float* __restrict__ e1, float* __restrict__ e2,
    unsigned int* __restrict__ adj) {
    int b = blockIdx.x;
    int t = threadIdx.x;
    int lane = t & 63, wv = t >> 6;
    int rt = b >> 2, head = b & 3;
    int row0 = rt * 16;
    int col0 = head * 64;

    __shared__ unsigned short As[16][LDA];     // full K=256
    __shared__ unsigned short Bs[64][LDBH];    // one K=128 half, reused
    __shared__ float s1[4][16], s2[4][16];

    // adj zero + self bits (head-0 blocks own rows [16rt,+16) = 512 uint4)
    if (head == 0) {
        uint4* adj4 = (uint4*)adj;
        #pragma unroll
        for (int q = 0; q < 2; ++q) {
            int g = rt * 512 + q * 256 + t;
            int r = g >> 5;
            int sw = r * WPR + (r >> 5);
            uint4 z{0u, 0u, 0u, 0u};
            if ((sw >> 2) == g) ((unsigned*)&z)[sw & 3] = 1u << (r & 31);
            adj4[g] = z;
        }
    }

    // ---- stage A: 16x256 fp32 -> bf16, 1024 float4 coalesced (4/thread)
    {
        const float4* src = (const float4*)(in + row0 * DD);
        #pragma unroll
        for (int i = 0; i < 4; ++i) {
            int e = i * 256 + t;
            int r = e >> 6, c4 = (e & 63) * 4;
            float4 v = src[e];
            unsigned short* dst = &As[r][c4];
            ((uint2*)dst)[0] = uint2{
                (unsigned)f2bf(v.x) | ((unsigned)f2bf(v.y) << 16),
                (unsigned)f2bf(v.z) | ((unsigned)f2bf(v.w) << 16)};
        }
    }

    // ---- K in two 128-halves: stage B-half transposed, sync, 4 MFMA steps
    int c4 = (t & 15) * 4;
    int kk = t >> 4;
    int kb = (lane >> 4) * 8;
    const unsigned short* Bp = &Bs[wv * 16 + (lane & 15)][0];
    f32x4 acc = {0.f, 0.f, 0.f, 0.f};
    #pragma unroll
    for (int p = 0; p < 2; ++p) {
        if (p) __syncthreads();                // phase-0 reads done before overwrite
        #pragma unroll
        for (int i = 0; i < 8; ++i) {
            int kl = i * 16 + kk;              // local k in [0,128)
            float4 w = *(const float4*)(W + (p * 128 + kl) * DD + col0 + c4);
            Bs[c4 + 0][kl] = f2bf(w.x);
            Bs[c4 + 1][kl] = f2bf(w.y);
            Bs[c4 + 2][kl] = f2bf(w.z);
            Bs[c4 + 3][kl] = f2bf(w.w);
        }
        __syncthreads();                       // covers As too (staged before)
        const unsigned short* Ap = &As[lane & 15][p * 128];
        #pragma unroll
        for (int s = 0; s < 4; ++s) {
            short8 af = *(const short8*)(Ap + s * 32 + kb);
            short8 bf = *(const short8*)(Bp + s * 32 + kb);
            acc = __builtin_amdgcn_mfma_f32_16x16x32_bf16(af, bf, acc, 0, 0, 0);
        }
    }

    // ---- store C (bf16) + e1/e2 epilogue (C/D: col=lane&15, row=(lane>>4)*4+r)
    int rg = lane >> 4, cl = lane & 15;
    int crow = row0 + rg * 4;
    int ccol = col0 + wv * 16 + cl;
    float a1w = att[wv * 16 + cl];
    float a2w = att[HIDD + wv * 16 + cl];
    float p1[4], p2[4];
    #pragma unroll
    for (int r = 0; r < 4; ++r) {
        Whb[(crow + r) * DD + ccol] = f2bf(acc[r]);
        p1[r] = acc[r] * a1w;
        p2[r] = acc[r] * a2w;
    }
    #pragma unroll
    for (int off = 1; off < 16; off <<= 1) {
        #pragma unroll
        for (int r = 0; r < 4; ++r) {
            p1[r] += __shfl_xor(p1[r], off);
            p2[r] += __shfl_xor(p2[r], off);
        }
    }
    if (cl == 0) {
        #pragma unroll
        for (int r = 0; r < 4; ++r) {
            s1[wv][rg * 4 + r] = p1[r];
            s2[wv][rg * 4 + r] = p2[r];
        }
    }
    __syncthreads();
    if (t < 16) {
        e1[(row0 + t) * NH + head] = s1[0][t] + s1[1][t] + s1[2][t] + s1[3][t];
        e2[(row0 + t) * NH + head] = s2[0][t] + s2[1][t] + s2[2][t] + s2[3][t];
    }
}

// ---------------------------------------------------------------- K2: edge bits (dedup via idempotent OR)
__global__ __launch_bounds__(256) void k2_build(
    const int* __restrict__ edges, unsigned int* __restrict__ adj) {
    int t = blockIdx.x * 256 + threadIdx.x;        // grid == NE exactly
    int r = edges[t * 3 + 0];
    int c = edges[t * 3 + 1];
    atomicOr(&adj[r * WPR + (c >> 5)], 1u << (c & 31));
}

// ---------------------------------------------------------------- K3: per-row GAT (prefix-scan compaction; no LDS-atomic chain)
__global__ __launch_bounds__(256) void k3_gat(
    const unsigned int* __restrict__ adj, const unsigned short* __restrict__ Whb,
    const float* __restrict__ e1, const float* __restrict__ e2,
    float* __restrict__ out) {
    int i    = blockIdx.x;
    int t    = threadIdx.x;
    int lane = t & 63, wid = t >> 6;

    __shared__ int   nbr[CAP];
    __shared__ float wgt[CAP][NH];
    __shared__ float zred[4][NH];
    __shared__ int   wtot[2];

    float4 e1q = *(const float4*)(e1 + i * NH);
    float  e1v[NH] = {e1q.x, e1q.y, e1q.z, e1q.w};

    // ---- scan 128 words: popcount -> wave prefix sum -> compacted writes
    unsigned wword = 0;
    int pc = 0;
    if (t < WPR) {
        wword = adj[i * WPR + t];
        pc = __popc(wword);
    }
    int incl = pc;
    #pragma unroll
    for (int off = 1; off < 64; off <<= 1) {
        int v = __shfl_up(incl, off);
        if (lane >= off) incl += v;
    }
    if (wid < 2 && lane == 63) wtot[wid] = incl;
    __syncthreads();
    int start = (wid == 1 ? wtot[0] : 0) + incl - pc;   // exclusive prefix
    int cn = wtot[0] + wtot[1];
    if (cn > CAP) cn = CAP;

    float zl[NH] = {0.f, 0.f, 0.f, 0.f};
    if (t < WPR) {
        int d = start;
        unsigned bits = wword;
        while (bits) {
            int bp = __ffs(bits) - 1;
            bits &= bits - 1;
            int j = t * 32 + bp;
            if (d < CAP) {
                nbr[d] = j;
                float4 ev = *(const float4*)(e2 + j * NH);
                float e2v[NH] = {ev.x, ev.y, ev.z, ev.w};
                #pragma unroll
                for (int h = 0; h < NH; ++h) {
                    float s = e1v[h] + e2v[h];
                    s = (s >= 0.f) ? s : SLOPE * s;      // LeakyReLU
                    float w = __expf(s);
                    wgt[d][h] = w;
                    zl[h] += w;
                }
            }
            ++d;
        }
    }
    // ---- block reduce Z (waves 2,3 contribute zeros)
    #pragma unroll
    for (int off = 32; off; off >>= 1) {
        #pragma unroll
        for (int h = 0; h < NH; ++h) zl[h] += __shfl_xor(zl[h], off);
    }
    if (lane == 0) {
        #pragma unroll
        for (int h = 0; h < NH; ++h) zred[wid][h] = zl[h];
    }
    __syncthreads();               // nbr/wgt/zred visible

    float Z = zred[0][wid] + zred[1][wid] + zred[2][wid] + zred[3][wid];

    // ---- gather: thread (h=wid, f=lane); bf16 row segment = 128B coalesced/wave
    float acc = 0.f;
    #pragma unroll 8
    for (int d = 0; d < cn; ++d)
        acc = fmaf(wgt[d][wid],
                   bf2f(Whb[nbr[d] * DD + wid * HIDD + lane]), acc);
    float r = acc / Z;
    out[i * DD + t] = (r > 0.f) ? r : (__expf(r) - 1.f);   // ELU(alpha=1)
}

// ---------------------------------------------------------------- launcher
extern "C" void kernel_launch(void* const* d_in, const int* in_sizes, int n_in,
                              void* d_out, int out_size, void* d_ws, size_t ws_size,
                              hipStream_t stream) {
    const float* inp   = (const float*)d_in[0];
    const int*   edges = (const int*)d_in[1];
    // d_in[2] = num_node (scalar, constant 4096) — unused
    const float* W     = (const float*)d_in[3];
    const float* att   = (const float*)d_in[4];
    float*       out   = (float*)d_out;

    char* ws = (char*)d_ws;
    unsigned short* Whb = (unsigned short*)(ws);                   // 2 MB
    float*        e1  = (float*)(ws + (2u << 20));                 // 64 KB
    float*        e2  = (float*)(ws + (2u << 20) + (64u << 10));   // 64 KB
    unsigned int* adj = (unsigned int*)(ws + (2u << 20) + (128u << 10)); // 2 MB

    k1_mfma_gemm<<<NN / 16 * NH, 256, 0, stream>>>(inp, W, att, Whb, e1, e2, adj);
    k2_build<<<NE / 256, 256, 0, stream>>>(edges, adj);
    k3_gat<<<NN, 256, 0, stream>>>(adj, Whb, e1, e2, out);
}

// Round 14
// 39.295 us; speedup vs baseline: 6.7861x; 1.0788x over previous
//
#include <hip/hip_runtime.h>

#define NN    4096      // nodes
#define DD    256       // feature dim (= H*HID)
#define NH    4         // heads
#define HIDD  64        // per-head hidden
#define NE    131072    // edges
#define WPR   (NN/32)   // 128 u32 words per adjacency bitmask row
#define SLOPE 0.2f
#define CAP   128       // max degree; Binom(131072,1/4096) max over 4096 rows ~56 incl self
#define LDBH  130       // Bs leading dim (shorts): 260B rows -> frag ds_read_b128 bank stride 1 (conflict-free)

typedef __attribute__((ext_vector_type(8))) short short8;   // 8 bf16 in 4 VGPRs
typedef __attribute__((ext_vector_type(4))) float f32x4;

__device__ __forceinline__ unsigned short f2bf(float x) {   // RNE, matches HW cvt
    unsigned u = __float_as_uint(x);
    u += 0x7fffu + ((u >> 16) & 1u);
    return (unsigned short)(u >> 16);
}
__device__ __forceinline__ float bf2f(unsigned short v) {
    return __uint_as_float((unsigned)v << 16);
}

// ---------------------------------------------------------------- K1: MFMA GEMM + adj-zero/self + fused e1/e2
// 1024 blocks x 256 thr. A: NO staging — each lane's A-frag is contiguous in
// `in` (row0+lane&15, k..k+7), loaded direct as 2x float4 + cvt; 4 waves share
// rows via L1. B: all 16 float4 loads ISSUED UP FRONT (max MLP), staged to
// LDS transposed in two K=128 halves; LDBH=130 -> conflict-free frag reads,
// 2-way (free) staging writes (R13 had 8-way, 3.9M conflict cycles).
__global__ __launch_bounds__(256, 4) void k1_mfma_gemm(
    const float* __restrict__ in, const float* __restrict__ W,
    const float* __restrict__ att, unsigned short* __restrict__ Whb,
    float* __restrict__ e1, float* __restrict__ e2,
    unsigned int* __restrict__ adj) {
    int b = blockIdx.x;
    int t = threadIdx.x;
    int lane = t & 63, wv = t >> 6;
    int rt = b >> 2, head = b & 3;
    int row0 = rt * 16;
    int col0 = head * 64;

    __shared__ unsigned short Bs[64][LDBH];    // one K=128 half, reused
    __shared__ float s1[4][16], s2[4][16];

    // ---- issue ALL B loads first (16 float4, both halves) for MLP
    int c4 = (t & 15) * 4;
    int kk = t >> 4;
    float4 b0[8], b1[8];
    #pragma unroll
    for (int i = 0; i < 8; ++i) {
        int kl = i * 16 + kk;
        b0[i] = *(const float4*)(W + kl * DD + col0 + c4);
        b1[i] = *(const float4*)(W + (128 + kl) * DD + col0 + c4);
    }

    // adj zero + self bits (head-0 blocks own rows [16rt,+16) = 512 uint4)
    if (head == 0) {
        uint4* adj4 = (uint4*)adj;
        #pragma unroll
        for (int q = 0; q < 2; ++q) {
            int g = rt * 512 + q * 256 + t;
            int r = g >> 5;
            int sw = r * WPR + (r >> 5);
            uint4 z{0u, 0u, 0u, 0u};
            if ((sw >> 2) == g) ((unsigned*)&z)[sw & 3] = 1u << (r & 31);
            adj4[g] = z;
        }
    }

    const float* Arow = in + (row0 + (lane & 15)) * DD;
    int kb = (lane >> 4) * 8;
    const unsigned short* Bp = &Bs[wv * 16 + (lane & 15)][0];
    f32x4 acc = {0.f, 0.f, 0.f, 0.f};

    // ---- half 0: stage b0, mfma; half 1: stage b1, mfma
    #pragma unroll
    for (int p = 0; p < 2; ++p) {
        if (p) __syncthreads();                // phase-0 frag reads done
        #pragma unroll
        for (int i = 0; i < 8; ++i) {
            int kl = i * 16 + kk;
            float4 w = p ? b1[i] : b0[i];
            Bs[c4 + 0][kl] = f2bf(w.x);
            Bs[c4 + 1][kl] = f2bf(w.y);
            Bs[c4 + 2][kl] = f2bf(w.z);
            Bs[c4 + 3][kl] = f2bf(w.w);
        }
        __syncthreads();
        #pragma unroll
        for (int s = 0; s < 4; ++s) {
            int k = p * 128 + s * 32 + kb;
            float4 x0 = *(const float4*)(Arow + k);
            float4 x1 = *(const float4*)(Arow + k + 4);
            short8 af, bf;
            af[0] = (short)f2bf(x0.x); af[1] = (short)f2bf(x0.y);
            af[2] = (short)f2bf(x0.z); af[3] = (short)f2bf(x0.w);
            af[4] = (short)f2bf(x1.x); af[5] = (short)f2bf(x1.y);
            af[6] = (short)f2bf(x1.z); af[7] = (short)f2bf(x1.w);
            bf = *(const short8*)(Bp + s * 32 + kb);
            acc = __builtin_amdgcn_mfma_f32_16x16x32_bf16(af, bf, acc, 0, 0, 0);
        }
    }

    // ---- store C (bf16) + e1/e2 epilogue (C/D: col=lane&15, row=(lane>>4)*4+r)
    int rg = lane >> 4, cl = lane & 15;
    int crow = row0 + rg * 4;
    int ccol = col0 + wv * 16 + cl;
    float a1w = att[wv * 16 + cl];
    float a2w = att[HIDD + wv * 16 + cl];
    float p1[4], p2[4];
    #pragma unroll
    for (int r = 0; r < 4; ++r) {
        Whb[(crow + r) * DD + ccol] = f2bf(acc[r]);
        p1[r] = acc[r] * a1w;
        p2[r] = acc[r] * a2w;
    }
    #pragma unroll
    for (int off = 1; off < 16; off <<= 1) {
        #pragma unroll
        for (int r = 0; r < 4; ++r) {
            p1[r] += __shfl_xor(p1[r], off);
            p2[r] += __shfl_xor(p2[r], off);
        }
    }
    if (cl == 0) {
        #pragma unroll
        for (int r = 0; r < 4; ++r) {
            s1[wv][rg * 4 + r] = p1[r];
            s2[wv][rg * 4 + r] = p2[r];
        }
    }
    __syncthreads();
    if (t < 16) {
        e1[(row0 + t) * NH + head] = s1[0][t] + s1[1][t] + s1[2][t] + s1[3][t];
        e2[(row0 + t) * NH + head] = s2[0][t] + s2[1][t] + s2[2][t] + s2[3][t];
    }
}

// ---------------------------------------------------------------- K2: edge bits (dedup via idempotent OR)
__global__ __launch_bounds__(256) void k2_build(
    const int* __restrict__ edges, unsigned int* __restrict__ adj) {
    int t = blockIdx.x * 256 + threadIdx.x;        // grid == NE exactly
    int r = edges[t * 3 + 0];
    int c = edges[t * 3 + 1];
    atomicOr(&adj[r * WPR + (c >> 5)], 1u << (c & 31));
}

// ---------------------------------------------------------------- K3: per-row GAT, 2 rows/block (2048 blocks)
// Waves {0,1} -> row 2b, {2,3} -> row 2b+1. Scan: 128 thr/row; prefix-scan
// compaction. Gather: wave pair per row, 2 heads per lane.
__global__ __launch_bounds__(256) void k3_gat(
    const unsigned int* __restrict__ adj, const unsigned short* __restrict__ Whb,
    const float* __restrict__ e1, const float* __restrict__ e2,
    float* __restrict__ out) {
    int b    = blockIdx.x;
    int t    = threadIdx.x;
    int lane = t & 63, wv = t >> 6;
    int hr   = t >> 7;                 // which of the 2 rows
    int i    = b * 2 + hr;
    int t2   = t & 127;                // thread within row group

    __shared__ int   nbr[2][CAP];
    __shared__ float wgt[2][CAP][NH];
    __shared__ float zred[4][NH];
    __shared__ int   wtot[4];

    float4 e1q = *(const float4*)(e1 + i * NH);
    float  e1v[NH] = {e1q.x, e1q.y, e1q.z, e1q.w};

    // ---- scan this row's 128 words: popcount -> prefix -> compacted writes
    unsigned wword = adj[i * WPR + t2];
    int pc = __popc(wword);
    int incl = pc;
    #pragma unroll
    for (int off = 1; off < 64; off <<= 1) {
        int v = __shfl_up(incl, off);
        if (lane >= off) incl += v;
    }
    if (lane == 63) wtot[wv] = incl;
    __syncthreads();
    int start = ((wv & 1) ? wtot[wv & 2] : 0) + incl - pc;   // exclusive prefix in row grp
    int cn = wtot[hr * 2] + wtot[hr * 2 + 1];
    if (cn > CAP) cn = CAP;

    float zl[NH] = {0.f, 0.f, 0.f, 0.f};
    {
        int d = start;
        unsigned bits = wword;
        while (bits) {
            int bp = __ffs(bits) - 1;
            bits &= bits - 1;
            int j = t2 * 32 + bp;
            if (d < CAP) {
                nbr[hr][d] = j;
                float4 ev = *(const float4*)(e2 + j * NH);
                float e2v[NH] = {ev.x, ev.y, ev.z, ev.w};
                #pragma unroll
                for (int h = 0; h < NH; ++h) {
                    float s = e1v[h] + e2v[h];
                    s = (s >= 0.f) ? s : SLOPE * s;      // LeakyReLU
                    float w = __expf(s);
                    wgt[hr][d][h] = w;
                    zl[h] += w;
                }
            }
            ++d;
        }
    }
    // ---- reduce Z within each wave, combine wave pair via LDS
    #pragma unroll
    for (int off = 32; off; off >>= 1) {
        #pragma unroll
        for (int h = 0; h < NH; ++h) zl[h] += __shfl_xor(zl[h], off);
    }
    if (lane == 0) {
        #pragma unroll
        for (int h = 0; h < NH; ++h) zred[wv][h] = zl[h];
    }
    __syncthreads();               // nbr/wgt/zred visible

    // ---- gather: wave pair per row; lane covers 2 heads (h0 = (wv&1)*2)
    int h0 = (wv & 1) * 2;
    float Za = zred[hr * 2][h0]     + zred[hr * 2 + 1][h0];
    float Zb = zred[hr * 2][h0 + 1] + zred[hr * 2 + 1][h0 + 1];
    float acca = 0.f, accb = 0.f;
    #pragma unroll 4
    for (int d = 0; d < cn; ++d) {
        int j = nbr[hr][d];
        const unsigned short* row = Whb + j * DD + h0 * HIDD + lane;
        acca = fmaf(wgt[hr][d][h0],     bf2f(row[0]),    acca);
        accb = fmaf(wgt[hr][d][h0 + 1], bf2f(row[HIDD]), accb);
    }
    float ra = acca / Za, rb = accb / Zb;
    out[i * DD + h0 * HIDD + lane]        = (ra > 0.f) ? ra : (__expf(ra) - 1.f);
    out[i * DD + (h0 + 1) * HIDD + lane]  = (rb > 0.f) ? rb : (__expf(rb) - 1.f);
}

// ---------------------------------------------------------------- launcher
extern "C" void kernel_launch(void* const* d_in, const int* in_sizes, int n_in,
                              void* d_out, int out_size, void* d_ws, size_t ws_size,
                              hipStream_t stream) {
    const float* inp   = (const float*)d_in[0];
    const int*   edges = (const int*)d_in[1];
    // d_in[2] = num_node (scalar, constant 4096) — unused
    const float* W     = (const float*)d_in[3];
    const float* att   = (const float*)d_in[4];
    float*       out   = (float*)d_out;

    char* ws = (char*)d_ws;
    unsigned short* Whb = (unsigned short*)(ws);                   // 2 MB
    float*        e1  = (float*)(ws + (2u << 20));                 // 64 KB
    float*        e2  = (float*)(ws + (2u << 20) + (64u << 10));   // 64 KB
    unsigned int* adj = (unsigned int*)(ws + (2u << 20) + (128u << 10)); // 2 MB

    k1_mfma_gemm<<<NN / 16 * NH, 256, 0, stream>>>(inp, W, att, Whb, e1, e2, adj);
    k2_build<<<NE / 256, 256, 0, stream>>>(edges, adj);
    k3_gat<<<NN / 2, 256, 0, stream>>>(adj, Whb, e1, e2, out);
}